// Round 4
// baseline (527.469 us; speedup 1.0000x reference)
//
#include <hip/hip_runtime.h>

// Problem constants (from reference setup_inputs)
constexpr int B = 512;
constexpr int N = 1000;    // rows per batch
constexpr int D = 128;
constexpr int F = 2;
constexpr float LN_EPS = 1e-3f;

constexpr int CHUNKS = 4;                   // row-chunks per batch
constexpr int ROWS_PER_CHUNK = N / CHUNKS;  // 250

// clang-native 4-float vector (accepted by __builtin_nontemporal_load)
typedef float fx4 __attribute__((ext_vector_type(4)));

// =====================================================================
// Fused kernel: streaming column-sum + "last block finishes" epilogue.
// grid = B*CHUNKS = 2048 blocks x 256 threads. Each block sums 250 rows
// (125 KB contiguous). The last-arriving block per batch (device-scope
// atomic counter) combines partials, gathers the 2 indexed rows, does
// the 384->128 matvec + ReLU + LayerNorm, and writes the output row.
// Deterministic: partial sums and the combine order are fixed; only
// WHICH block runs the epilogue varies.
// =====================================================================
__global__ __launch_bounds__(256) void fused_colsum_finish(
    const float* __restrict__ H, const int* __restrict__ indice,
    const float* __restrict__ W, const float* __restrict__ bias,
    const float* __restrict__ gamma, const float* __restrict__ beta,
    float* __restrict__ partials, int* __restrict__ counters,
    float* __restrict__ out)
{
    const int blk = blockIdx.x;
    const int b   = blk >> 2;          // batch
    const int ch  = blk & 3;           // chunk
    const int tid = threadIdx.x;
    const int c4  = tid & 31;          // which fx4 of the 128-float row
    const int rg  = tid >> 5;          // row group 0..7

    const float* __restrict__ Hb = H + (size_t)b * (N * D);
    const int nstart = ch * ROWS_PER_CHUNK;
    const int nend   = nstart + ROWS_PER_CHUNK;

    // ---- streaming phase: 8 loads in flight per thread ----
    fx4 acc = (fx4)(0.f);
    #pragma unroll 8
    for (int n = nstart + rg; n < nend; n += 8) {
        acc += __builtin_nontemporal_load(
            reinterpret_cast<const fx4*>(Hb + (size_t)n * D + c4 * 4));
    }

    __shared__ fx4 sp[8][32];
    sp[rg][c4] = acc;
    __syncthreads();

    if (tid < 32) {
        fx4 s = sp[0][tid];
        #pragma unroll
        for (int g = 1; g < 8; ++g) s += sp[g][tid];
        reinterpret_cast<fx4*>(partials)[(size_t)(b * CHUNKS + ch) * 32 + tid] = s;
    }

    // ---- publish partial (release) and elect the finisher ----
    __shared__ int slast;
    __threadfence();                    // writers: make partial device-visible
    __syncthreads();
    if (tid == 0) {
        const int old = atomicAdd(&counters[b], 1);
        slast = (old == CHUNKS - 1);
    }
    __syncthreads();
    if (!slast) return;
    __threadfence();                    // acquire: see other blocks' partials

    // ---- epilogue (finisher block only; all 256 threads, o duplicated) ----
    const int o = tid & 127;            // output element; waves 2,3 duplicate

    __shared__ float semb[(F + 1) * D]; // [row_i0 | row_i1 | mean]
    __shared__ float sred[4], sred2[4];

    if (tid < 128) {
        const int i0 = indice[b * F + 0];
        const int i1 = indice[b * F + 1];
        semb[o]     = Hb[i0 * D + o];
        semb[D + o] = Hb[i1 * D + o];
        const float cs = partials[(size_t)(b * CHUNKS + 0) * D + o]
                       + partials[(size_t)(b * CHUNKS + 1) * D + o]
                       + partials[(size_t)(b * CHUNKS + 2) * D + o]
                       + partials[(size_t)(b * CHUNKS + 3) * D + o];
        semb[2 * D + o] = cs * (1.0f / (float)N);
    }
    __syncthreads();

    // matvec: x[o] = sum_k emb[k] * W[k,o], 4 independent accumulators
    float x0 = bias[o], x1 = 0.f, x2 = 0.f, x3 = 0.f;
    #pragma unroll 8
    for (int k = 0; k < (F + 1) * D; k += 4) {
        x0 = fmaf(semb[k + 0], W[(k + 0) * D + o], x0);
        x1 = fmaf(semb[k + 1], W[(k + 1) * D + o], x1);
        x2 = fmaf(semb[k + 2], W[(k + 2) * D + o], x2);
        x3 = fmaf(semb[k + 3], W[(k + 3) * D + o], x3);
    }
    const float x = fmaxf((x0 + x1) + (x2 + x3), 0.f);

    // LayerNorm: 128 values; waves 0,1 hold o=0..127, waves 2,3 duplicates
    float s = x, s2 = x * x;
    #pragma unroll
    for (int off = 1; off < 64; off <<= 1) {
        s  += __shfl_xor(s,  off);
        s2 += __shfl_xor(s2, off);
    }
    const int wid = tid >> 6;
    if ((tid & 63) == 0) { sred[wid] = s; sred2[wid] = s2; }
    __syncthreads();
    const float S  = sred[0]  + sred[1];   // waves 2,3 are duplicates — ignore
    const float S2 = sred2[0] + sred2[1];
    const float mean = S * (1.0f / (float)D);
    const float var  = S2 * (1.0f / (float)D) - mean * mean;
    const float rstd = rsqrtf(var + LN_EPS);

    out[(size_t)b * D + o] = gamma[o] * (x - mean) * rstd + beta[o];
}

// =====================================================================
// Fallback path (two kernels) if ws is too small for the counter array.
// =====================================================================
__global__ __launch_bounds__(256) void colsum_kernel(
    const float* __restrict__ H, fx4* __restrict__ ws)
{
    const int blk = blockIdx.x;
    const int b   = blk >> 2;
    const int ch  = blk & 3;
    const int tid = threadIdx.x;
    const int c4  = tid & 31;
    const int rg  = tid >> 5;

    const float* __restrict__ Hb = H + (size_t)b * (N * D);
    const int nstart = ch * ROWS_PER_CHUNK;
    const int nend   = nstart + ROWS_PER_CHUNK;

    fx4 acc = (fx4)(0.f);
    #pragma unroll 8
    for (int n = nstart + rg; n < nend; n += 8) {
        acc += __builtin_nontemporal_load(
            reinterpret_cast<const fx4*>(Hb + (size_t)n * D + c4 * 4));
    }

    __shared__ fx4 sp[8][32];
    sp[rg][c4] = acc;
    __syncthreads();

    if (tid < 32) {
        fx4 s = sp[0][tid];
        #pragma unroll
        for (int g = 1; g < 8; ++g) s += sp[g][tid];
        ws[(size_t)(b * CHUNKS + ch) * 32 + tid] = s;
    }
}

__global__ __launch_bounds__(128) void gather_dense_ln(
    const float* __restrict__ H, const int* __restrict__ indice,
    const float* __restrict__ ws, const float* __restrict__ W,
    const float* __restrict__ bias, const float* __restrict__ gamma,
    const float* __restrict__ beta, float* __restrict__ out)
{
    const int b = blockIdx.x;
    const int o = threadIdx.x;

    __shared__ float semb[(F + 1) * D];
    __shared__ float sred[2], sred2[2];

    const float* __restrict__ Hb = H + (size_t)b * (N * D);
    const int i0 = indice[b * F + 0];
    const int i1 = indice[b * F + 1];
    semb[o]     = Hb[i0 * D + o];
    semb[D + o] = Hb[i1 * D + o];
    const float cs = ws[(size_t)(b * CHUNKS + 0) * D + o]
                   + ws[(size_t)(b * CHUNKS + 1) * D + o]
                   + ws[(size_t)(b * CHUNKS + 2) * D + o]
                   + ws[(size_t)(b * CHUNKS + 3) * D + o];
    semb[2 * D + o] = cs * (1.0f / (float)N);
    __syncthreads();

    float x0 = bias[o], x1 = 0.f, x2 = 0.f, x3 = 0.f;
    #pragma unroll 8
    for (int k = 0; k < (F + 1) * D; k += 4) {
        x0 = fmaf(semb[k + 0], W[(k + 0) * D + o], x0);
        x1 = fmaf(semb[k + 1], W[(k + 1) * D + o], x1);
        x2 = fmaf(semb[k + 2], W[(k + 2) * D + o], x2);
        x3 = fmaf(semb[k + 3], W[(k + 3) * D + o], x3);
    }
    float x = fmaxf((x0 + x1) + (x2 + x3), 0.f);

    float s = x, s2 = x * x;
    #pragma unroll
    for (int off = 1; off < 64; off <<= 1) {
        s  += __shfl_xor(s,  off);
        s2 += __shfl_xor(s2, off);
    }
    const int wid = o >> 6;
    if ((o & 63) == 0) { sred[wid] = s; sred2[wid] = s2; }
    __syncthreads();
    const float S  = sred[0]  + sred[1];
    const float S2 = sred2[0] + sred2[1];
    const float mean = S * (1.0f / (float)D);
    const float var  = S2 * (1.0f / (float)D) - mean * mean;
    const float rstd = rsqrtf(var + LN_EPS);

    out[(size_t)b * D + o] = gamma[o] * (x - mean) * rstd + beta[o];
}

extern "C" void kernel_launch(void* const* d_in, const int* in_sizes, int n_in,
                              void* d_out, int out_size, void* d_ws, size_t ws_size,
                              hipStream_t stream) {
    const float* H      = (const float*)d_in[0];
    const int*   indice = (const int*)  d_in[1];
    const float* W      = (const float*)d_in[2];
    const float* bias   = (const float*)d_in[3];
    const float* gamma  = (const float*)d_in[4];
    const float* beta   = (const float*)d_in[5];
    float* out = (float*)d_out;

    float* partials = (float*)d_ws;                       // B*CHUNKS*D floats = 1 MB
    const size_t partial_bytes = (size_t)B * CHUNKS * D * sizeof(float);
    const size_t need = partial_bytes + (size_t)B * sizeof(int);

    if (ws_size >= need) {
        int* counters = (int*)((char*)d_ws + partial_bytes);
        hipMemsetAsync(counters, 0, (size_t)B * sizeof(int), stream);
        fused_colsum_finish<<<dim3(B * CHUNKS), dim3(256), 0, stream>>>(
            H, indice, W, bias, gamma, beta, partials, counters, out);
    } else {
        colsum_kernel<<<dim3(B * CHUNKS), dim3(256), 0, stream>>>(
            H, reinterpret_cast<fx4*>(partials));
        gather_dense_ln<<<dim3(B), dim3(128), 0, stream>>>(
            H, indice, partials, W, bias, gamma, beta, out);
    }
}

// Round 5
// 53.709 us; speedup vs baseline: 9.8209x; 9.8209x over previous
//
#include <hip/hip_runtime.h>

// Problem constants (from reference setup_inputs)
constexpr int B = 512;
constexpr int N = 1000;    // rows per batch
constexpr int D = 128;
constexpr int F = 2;
constexpr float LN_EPS = 1e-3f;

// Batches < NT_SPLIT use plain loads (L3-cacheable: 448*512KB = 229 MB < 256 MB IC);
// batches >= NT_SPLIT stream with nontemporal loads so they don't thrash the rest.
constexpr int NT_SPLIT = 448;

// clang-native 4-float vector (accepted by __builtin_nontemporal_load)
typedef float fx4 __attribute__((ext_vector_type(4)));

// ---------------- Kernel A: streaming column sums ----------------
// grid = B*CH blocks x 256 threads. Each block sums N/CH rows of one batch
// into ws[(b*CH+ch)*32 + c4] (fx4 units).
template<int CH>
__global__ __launch_bounds__(256) void colsum_kernel(
    const float* __restrict__ H, fx4* __restrict__ ws)
{
    constexpr int RPC = N / CH;        // rows per chunk (1000/8=125, 1000/4=250)
    const int blk = blockIdx.x;
    const int b   = blk / CH;
    const int ch  = blk % CH;
    const int tid = threadIdx.x;
    const int c4  = tid & 31;          // which fx4 of the 128-float row
    const int rg  = tid >> 5;          // row group 0..7

    const float* __restrict__ Hb = H + (size_t)b * (N * D);
    const int nstart = ch * RPC;
    const int nend   = nstart + RPC;

    fx4 acc = (fx4)(0.f);
    if (b < NT_SPLIT) {
        #pragma unroll 8
        for (int n = nstart + rg; n < nend; n += 8)
            acc += *reinterpret_cast<const fx4*>(Hb + (size_t)n * D + c4 * 4);
    } else {
        #pragma unroll 8
        for (int n = nstart + rg; n < nend; n += 8)
            acc += __builtin_nontemporal_load(
                reinterpret_cast<const fx4*>(Hb + (size_t)n * D + c4 * 4));
    }

    __shared__ fx4 sp[8][32];
    sp[rg][c4] = acc;
    __syncthreads();

    if (tid < 32) {
        fx4 s = sp[0][tid];
        #pragma unroll
        for (int g = 1; g < 8; ++g) s += sp[g][tid];
        ws[(size_t)(b * CH + ch) * 32 + tid] = s;
    }
}

// ---------------- Kernel B: gather + dense + ReLU + LayerNorm ----------------
// grid = B blocks x 256 threads. Matvec split 8-way over K (ksl = tid>>5 owns
// 48 k's), each thread holds 4 output columns as fx4; combine + LN on wave 0.
template<int CH>
__global__ __launch_bounds__(256) void gather_dense_ln(
    const float* __restrict__ H, const int* __restrict__ indice,
    const float* __restrict__ ws, const float* __restrict__ W,
    const float* __restrict__ bias, const float* __restrict__ gamma,
    const float* __restrict__ beta, float* __restrict__ out)
{
    const int b   = blockIdx.x;
    const int tid = threadIdx.x;
    const float* __restrict__ Hb = H + (size_t)b * (N * D);

    __shared__ float semb[(F + 1) * D];  // [row_i0 | row_i1 | mean]
    __shared__ fx4 sx[8][32];            // per-k-slice partial outputs

    // gather the two indexed rows: 256 threads cover 2*128 elements
    {
        const int f   = tid >> 7;            // 0 or 1
        const int col = tid & 127;
        const int idx = indice[b * F + f];
        semb[f * D + col] = Hb[(size_t)idx * D + col];
    }
    // mean row from partials: threads 0..127
    if (tid < 128) {
        float cs = 0.f;
        #pragma unroll
        for (int g = 0; g < CH; ++g)
            cs += reinterpret_cast<const float*>(ws)[(size_t)(b * CH + g) * D + tid];
        semb[2 * D + tid] = cs * (1.0f / (float)N);
    }
    __syncthreads();

    // matvec: slice ksl covers k in [ksl*48, ksl*48+48), 4 indep accumulators
    {
        const int ksl = tid >> 5;
        const int c4  = tid & 31;
        const fx4* __restrict__ W4 = reinterpret_cast<const fx4*>(W);
        fx4 a0 = (fx4)(0.f), a1 = (fx4)(0.f), a2 = (fx4)(0.f), a3 = (fx4)(0.f);
        const int k0 = ksl * 48;
        #pragma unroll 4
        for (int k = k0; k < k0 + 48; k += 4) {
            a0 += semb[k + 0] * W4[(size_t)(k + 0) * 32 + c4];
            a1 += semb[k + 1] * W4[(size_t)(k + 1) * 32 + c4];
            a2 += semb[k + 2] * W4[(size_t)(k + 2) * 32 + c4];
            a3 += semb[k + 3] * W4[(size_t)(k + 3) * 32 + c4];
        }
        sx[ksl][c4] = (a0 + a1) + (a2 + a3);
    }
    __syncthreads();

    // combine slices + bias + ReLU + LayerNorm on wave 0 (lanes 0..31, 4 cols each)
    if (tid < 32) {
        fx4 x = reinterpret_cast<const fx4*>(bias)[tid];
        #pragma unroll
        for (int g = 0; g < 8; ++g) x += sx[g][tid];
        x.x = fmaxf(x.x, 0.f); x.y = fmaxf(x.y, 0.f);
        x.z = fmaxf(x.z, 0.f); x.w = fmaxf(x.w, 0.f);

        float s  = x.x + x.y + x.z + x.w;
        float s2 = x.x * x.x + x.y * x.y + x.z * x.z + x.w * x.w;
        #pragma unroll
        for (int off = 1; off < 32; off <<= 1) {   // lanes 0..31 only: partners stay active
            s  += __shfl_xor(s,  off);
            s2 += __shfl_xor(s2, off);
        }
        const float mean = s  * (1.0f / (float)D);
        const float var  = s2 * (1.0f / (float)D) - mean * mean;
        const float rstd = rsqrtf(var + LN_EPS);

        const fx4 g4 = reinterpret_cast<const fx4*>(gamma)[tid];
        const fx4 b4 = reinterpret_cast<const fx4*>(beta)[tid];
        fx4 y;
        y.x = g4.x * (x.x - mean) * rstd + b4.x;
        y.y = g4.y * (x.y - mean) * rstd + b4.y;
        y.z = g4.z * (x.z - mean) * rstd + b4.z;
        y.w = g4.w * (x.w - mean) * rstd + b4.w;
        reinterpret_cast<fx4*>(out)[(size_t)b * 32 + tid] = y;
    }
}

extern "C" void kernel_launch(void* const* d_in, const int* in_sizes, int n_in,
                              void* d_out, int out_size, void* d_ws, size_t ws_size,
                              hipStream_t stream) {
    const float* H      = (const float*)d_in[0];
    const int*   indice = (const int*)  d_in[1];
    const float* W      = (const float*)d_in[2];
    const float* bias   = (const float*)d_in[3];
    const float* gamma  = (const float*)d_in[4];
    const float* beta   = (const float*)d_in[5];
    float* out = (float*)d_out;
    fx4*   ws  = (fx4*)d_ws;

    const size_t need8 = (size_t)B * 8 * D * sizeof(float);   // 2 MB
    if (ws_size >= need8) {
        colsum_kernel<8><<<dim3(B * 8), dim3(256), 0, stream>>>(H, ws);
        gather_dense_ln<8><<<dim3(B), dim3(256), 0, stream>>>(
            H, indice, (const float*)ws, W, bias, gamma, beta, out);
    } else {
        colsum_kernel<4><<<dim3(B * 4), dim3(256), 0, stream>>>(H, ws);
        gather_dense_ln<4><<<dim3(B), dim3(256), 0, stream>>>(
            H, indice, (const float*)ws, W, bias, gamma, beta, out);
    }
}

// Round 6
// 50.776 us; speedup vs baseline: 10.3881x; 1.0578x over previous
//
#include <hip/hip_runtime.h>

// Problem constants (from reference setup_inputs)
constexpr int B = 512;
constexpr int N = 1000;    // rows per batch
constexpr int D = 128;
constexpr int F = 2;
constexpr float LN_EPS = 1e-3f;

constexpr int CHUNKS = 4;                   // row-chunks per batch (round-2 known-good)
constexpr int ROWS_PER_CHUNK = N / CHUNKS;  // 250

// clang-native 4-float vector (accepted by __builtin_nontemporal_load)
typedef float fx4 __attribute__((ext_vector_type(4)));

// ---------------- Kernel A: streaming column sums ----------------
// grid = B*CHUNKS = 2048 blocks x 256 threads (8 blocks/CU, full occupancy).
// Each block sums 250 rows (125 KB contiguous) with nontemporal fx4 loads
// (bypass L2 — zero reuse) into ws[(b*CHUNKS+ch)*32 + c4].
__global__ __launch_bounds__(256) void colsum_kernel(
    const float* __restrict__ H, fx4* __restrict__ ws)
{
    const int blk = blockIdx.x;
    const int b   = blk >> 2;          // batch
    const int ch  = blk & 3;           // chunk
    const int tid = threadIdx.x;
    const int c4  = tid & 31;          // which fx4 of the 128-float row
    const int rg  = tid >> 5;          // row group 0..7

    const float* __restrict__ Hb = H + (size_t)b * (N * D);
    const int nstart = ch * ROWS_PER_CHUNK;
    const int nend   = nstart + ROWS_PER_CHUNK;

    fx4 acc = (fx4)(0.f);
    #pragma unroll 8
    for (int n = nstart + rg; n < nend; n += 8)
        acc += __builtin_nontemporal_load(
            reinterpret_cast<const fx4*>(Hb + (size_t)n * D + c4 * 4));

    __shared__ fx4 sp[8][32];
    sp[rg][c4] = acc;
    __syncthreads();

    if (tid < 32) {
        fx4 s = sp[0][tid];
        #pragma unroll
        for (int g = 1; g < 8; ++g) s += sp[g][tid];
        ws[(size_t)(b * CHUNKS + ch) * 32 + tid] = s;   // plain store: keep L2-hot for B
    }
}

// ---------------- Kernel B: gather + dense + ReLU + LayerNorm ----------------
// grid = B blocks x 256 threads. Matvec split 8-way over K (each k-slice owns
// 48 k's, fx4 W loads -> 48 loads/thread); LDS combine; LN on wave-0 lanes 0..31.
__global__ __launch_bounds__(256) void gather_dense_ln(
    const float* __restrict__ H, const int* __restrict__ indice,
    const float* __restrict__ ws, const float* __restrict__ W,
    const float* __restrict__ bias, const float* __restrict__ gamma,
    const float* __restrict__ beta, float* __restrict__ out)
{
    const int b   = blockIdx.x;
    const int tid = threadIdx.x;
    const float* __restrict__ Hb = H + (size_t)b * (N * D);

    __shared__ float semb[(F + 1) * D];  // [row_i0 | row_i1 | mean]
    __shared__ fx4 sx[8][32];            // per-k-slice partial outputs

    // gather the two indexed rows: 256 threads cover 2*128 elements
    {
        const int f   = tid >> 7;            // 0 or 1
        const int col = tid & 127;
        const int idx = indice[b * F + f];
        semb[f * D + col] = Hb[(size_t)idx * D + col];
    }
    // mean row from the 4 chunk partials: threads 0..127
    if (tid < 128) {
        const float* wsf = reinterpret_cast<const float*>(ws);
        const float cs = wsf[(size_t)(b * CHUNKS + 0) * D + tid]
                       + wsf[(size_t)(b * CHUNKS + 1) * D + tid]
                       + wsf[(size_t)(b * CHUNKS + 2) * D + tid]
                       + wsf[(size_t)(b * CHUNKS + 3) * D + tid];
        semb[2 * D + tid] = cs * (1.0f / (float)N);
    }
    __syncthreads();

    // matvec: slice ksl covers k in [ksl*48, ksl*48+48), 4 indep accumulators
    {
        const int ksl = tid >> 5;
        const int c4  = tid & 31;
        const fx4* __restrict__ W4 = reinterpret_cast<const fx4*>(W);
        fx4 a0 = (fx4)(0.f), a1 = (fx4)(0.f), a2 = (fx4)(0.f), a3 = (fx4)(0.f);
        const int k0 = ksl * 48;
        #pragma unroll 4
        for (int k = k0; k < k0 + 48; k += 4) {
            a0 += semb[k + 0] * W4[(size_t)(k + 0) * 32 + c4];
            a1 += semb[k + 1] * W4[(size_t)(k + 1) * 32 + c4];
            a2 += semb[k + 2] * W4[(size_t)(k + 2) * 32 + c4];
            a3 += semb[k + 3] * W4[(size_t)(k + 3) * 32 + c4];
        }
        sx[ksl][c4] = (a0 + a1) + (a2 + a3);
    }
    __syncthreads();

    // combine slices + bias + ReLU + LayerNorm (wave 0, lanes 0..31, 4 cols each)
    if (tid < 32) {
        fx4 x = reinterpret_cast<const fx4*>(bias)[tid];
        #pragma unroll
        for (int g = 0; g < 8; ++g) x += sx[g][tid];
        x.x = fmaxf(x.x, 0.f); x.y = fmaxf(x.y, 0.f);
        x.z = fmaxf(x.z, 0.f); x.w = fmaxf(x.w, 0.f);

        float s  = x.x + x.y + x.z + x.w;
        float s2 = x.x * x.x + x.y * x.y + x.z * x.z + x.w * x.w;
        #pragma unroll
        for (int off = 1; off < 32; off <<= 1) {   // lanes 0..31: partners all active
            s  += __shfl_xor(s,  off);
            s2 += __shfl_xor(s2, off);
        }
        const float mean = s  * (1.0f / (float)D);
        const float var  = s2 * (1.0f / (float)D) - mean * mean;
        const float rstd = rsqrtf(var + LN_EPS);

        const fx4 g4 = reinterpret_cast<const fx4*>(gamma)[tid];
        const fx4 b4 = reinterpret_cast<const fx4*>(beta)[tid];
        fx4 y;
        y.x = g4.x * (x.x - mean) * rstd + b4.x;
        y.y = g4.y * (x.y - mean) * rstd + b4.y;
        y.z = g4.z * (x.z - mean) * rstd + b4.z;
        y.w = g4.w * (x.w - mean) * rstd + b4.w;
        reinterpret_cast<fx4*>(out)[(size_t)b * 32 + tid] = y;
    }
}

extern "C" void kernel_launch(void* const* d_in, const int* in_sizes, int n_in,
                              void* d_out, int out_size, void* d_ws, size_t ws_size,
                              hipStream_t stream) {
    const float* H      = (const float*)d_in[0];
    const int*   indice = (const int*)  d_in[1];
    const float* W      = (const float*)d_in[2];
    const float* bias   = (const float*)d_in[3];
    const float* gamma  = (const float*)d_in[4];
    const float* beta   = (const float*)d_in[5];
    float* out = (float*)d_out;
    fx4*   ws  = (fx4*)d_ws;   // needs B*CHUNKS*D floats = 1 MB

    colsum_kernel<<<dim3(B * CHUNKS), dim3(256), 0, stream>>>(H, ws);
    gather_dense_ln<<<dim3(B), dim3(256), 0, stream>>>(
        H, indice, (const float*)ws, W, bias, gamma, beta, out);
}